// Round 16
// baseline (199.529 us; speedup 1.0000x reference)
//
#include <hip/hip_runtime.h>
#include <hip/hip_bf16.h>
#include <hip/hip_fp16.h>
#include <cstdint>

#define HWS 3136
#define WID 56
#define NKQ 307328.0f   // 2 * 49 * 3136
#define X3SCALE 2048.0f
#define X3INV   (1.0f / 2048.0f)

// f32 parameter block ("small", at ws byte offset 704), element offsets:
#define S_CW1 0      // 288  (16x18)
#define S_CW2 288    // 512  (32x16)
#define S_CB2 800    // 32
#define S_WP  832    // 4
#define S_G1  836    // 18
#define S_BE1 854    // 18
#define S_G2  872    // 16
#define S_BE2 888    // 16
#define S_TOT 904
#define NWT   73728  // 256*288 transposed weights

__device__ __forceinline__ int refl(int i) {
  if (i < 0) i = -i;
  if (i >= WID) i = 2 * WID - 2 - i;
  return i;
}

// ---------------------------------------------------------------------------
// Kernel 0: pack small params + build wT[c][288] in d_out scratch.
// ---------------------------------------------------------------------------
__global__ __launch_bounds__(256) void k_prep(
    const float* __restrict__ w1, const float* __restrict__ w2,
    const float* __restrict__ w3,
    const float* __restrict__ cw1, const float* __restrict__ cw2,
    const float* __restrict__ cb2, const float* __restrict__ wp,
    const float* __restrict__ g1, const float* __restrict__ be1,
    const float* __restrict__ g2, const float* __restrict__ be2,
    float* __restrict__ small, float* __restrict__ wT)
{
  int e = blockIdx.x * 256 + threadIdx.x;
  if (e < S_TOT) {
    float v;
    if (e < S_CW2)      v = cw1[e];
    else if (e < S_CB2) v = cw2[e - S_CW2];
    else if (e < S_WP)  v = cb2[e - S_CB2];
    else if (e < S_G1)  v = wp [e - S_WP];
    else if (e < S_BE1) v = g1 [e - S_G1];
    else if (e < S_G2)  v = be1[e - S_BE1];
    else if (e < S_BE2) v = g2 [e - S_G2];
    else                v = be2[e - S_BE2];
    small[e] = v;
  }
  int et = e - S_TOT;
  if (et >= 0 && et < NWT) {
    int c = et / 288, r = et - (et / 288) * 288;
    float v = (r < 16) ? w1[r * 256 + c]
            : (r < 32) ? w2[(r - 16) * 256 + c]
                       : w3[(r - 32) * 256 + c];
    wT[et] = v;   // wT[c*288 + r]
  }
}

// ---------------------------------------------------------------------------
// Kernel 1: lane = pixel, rows via wave-uniform (scalar) weight loads.
// XCD-aware swizzle: all 16 row-chunks of one pixel-chunk land on the same
// XCD (assuming XCD = blockIdx % 8 round-robin), so x columns are fetched
// from HBM once chip-wide and served from that XCD's L2 for the other 15.
// grid = 1664 (8 * 13 * 16; 96 pad blocks exit).
// ---------------------------------------------------------------------------
__global__ __launch_bounds__(64) void k_proj(
    const float* __restrict__ x, const float* __restrict__ wT,
    const float* __restrict__ b1, const float* __restrict__ b2,
    const float* __restrict__ b3,
    float* __restrict__ x1t, float* __restrict__ x2t, short* __restrict__ x3i)
{
  const int bid = blockIdx.x;
  const int c8 = bid & 7;
  const int t8 = bid >> 3;
  const int rc = t8 & 15;
  const int pck = (t8 >> 4) * 8 + c8;
  if (pck >= 98) return;

  const int lane = threadIdx.x;
  const int r0 = rc * 18;
  const int P = pck * 64 + lane;
  const int n = P / HWS;

  float acc[18];
  #pragma unroll
  for (int i = 0; i < 18; i++) {
    int r = r0 + i;
    acc[i] = (r < 16) ? b1[r] : (r < 32) ? b2[r - 16] : b3[r - 32];
  }

  const float* xc = x + (size_t)n * 256 * HWS + (P - n * HWS);
  const float* wt0 = wT + r0;
  #pragma unroll 8
  for (int c = 0; c < 256; c++) {
    float xv = xc[(size_t)c * HWS];
    const float* wt = wt0 + c * 288;
    #pragma unroll
    for (int i = 0; i < 18; i++)
      acc[i] = fmaf(wt[i], xv, acc[i]);
  }

  #pragma unroll
  for (int i = 0; i < 18; i++) {
    int r = r0 + i;
    if (r < 16)
      x1t[(size_t)P * 16 + r] = acc[i];
    else if (r < 32)
      x2t[(size_t)P * 16 + (r - 16)] = acc[i];
    else {
      float cl = fminf(fmaxf(acc[i], -15.9f), 15.9f);
      x3i[(size_t)P * 256 + (r - 32)] = (short)__float2int_rn(cl * X3SCALE);
    }
  }
}

// ---------------------------------------------------------------------------
// Kernel 2a: row-pass 7-tap reflect box-sum of x2t -> R[p][16] (d_out scratch)
// ---------------------------------------------------------------------------
__global__ __launch_bounds__(256) void k_rowbox(
    const float* __restrict__ x2t, float* __restrict__ R)
{
  int idx = blockIdx.x * 256 + threadIdx.x;   // 98*256 = 6272*4
  int p = idx >> 2, cq = (idx & 3) * 4;
  int n = p / HWS, q = p % HWS;
  int y = q / WID, xx = q - y * WID;
  float4 s = {0.f, 0.f, 0.f, 0.f};
  #pragma unroll
  for (int d = -3; d <= 3; d++) {
    int nx = refl(xx + d);
    float4 v = *(const float4*)(x2t + (size_t)(n * HWS + y * WID + nx) * 16 + cq);
    s.x += v.x; s.y += v.y; s.z += v.z; s.w += v.w;
  }
  *(float4*)(R + (size_t)p * 16 + cq) = s;
}

// ---------------------------------------------------------------------------
// Kernel 2b: closed-form BN1 stat parts.
// ---------------------------------------------------------------------------
__global__ __launch_bounds__(256) void k_bn1(
    const float* __restrict__ x1t, const float* __restrict__ x2t,
    const float* __restrict__ R, const float* __restrict__ small,
    float* __restrict__ parts)
{
  __shared__ float cxs[56];
  __shared__ float red[4][4][20];
  __shared__ float pred[4][4];
  const int tid = threadIdx.x;
  if (tid < 56) {
    int cnt = 0;
    for (int xx = 0; xx < 56; xx++)
      for (int d = -3; d <= 3; d++)
        if (refl(xx + d) == tid) cnt++;
    cxs[tid] = (float)cnt;
  }
  __syncthreads();

  const int idx = blockIdx.x * 256 + tid;     // 98*256 = 6272*4
  const int p = idx >> 2, cq = (idx & 3) * 4;
  const int n = p / HWS, q = p % HWS;
  const int y = q / WID, xx = q - y * WID;

  float4 x1v = *(const float4*)(x1t + (size_t)p * 16 + cq);
  float4 x2v = *(const float4*)(x2t + (size_t)p * 16 + cq);
  float4 b2 = {0.f, 0.f, 0.f, 0.f};
  #pragma unroll
  for (int d = -3; d <= 3; d++) {
    int ny = refl(y + d);
    float4 v = *(const float4*)(R + (size_t)(n * HWS + ny * WID + xx) * 16 + cq);
    b2.x += v.x; b2.y += v.y; b2.z += v.z; b2.w += v.w;
  }
  float cnt = cxs[y] * cxs[xx];

  float a[20];
  {
    float xv[4] = {x1v.x, x1v.y, x1v.z, x1v.w};
    float x2a[4] = {x2v.x, x2v.y, x2v.z, x2v.w};
    float bb[4] = {b2.x, b2.y, b2.z, b2.w};
    #pragma unroll
    for (int j = 0; j < 4; j++) {
      a[j*5+0] = xv[j];
      a[j*5+1] = xv[j] * xv[j];
      a[j*5+2] = xv[j] * bb[j];
      a[j*5+3] = cnt * x2a[j];
      a[j*5+4] = cnt * x2a[j] * x2a[j];
    }
  }
  #pragma unroll
  for (int i = 0; i < 20; i++) {
    #pragma unroll
    for (int off = 4; off <= 32; off <<= 1)
      a[i] += __shfl_xor(a[i], off);
  }
  const int lane = tid & 63, wv = tid >> 6;
  if (lane < 4) {
    #pragma unroll
    for (int i = 0; i < 20; i++) red[wv][lane][i] = a[i];
  }

  float ps[4] = {0.f, 0.f, 0.f, 0.f};
  const float wp00 = small[S_WP+0], wp01 = small[S_WP+1];
  const float wp10 = small[S_WP+2], wp11 = small[S_WP+3];
  for (int it = idx; it < 153664; it += 25088) {
    int k = it / 3136, qq = it - (it / 3136) * 3136;
    int yy = qq / WID, xq = qq - yy * WID;
    int ny = refl(yy + k / 7 - 3), nx = refl(xq + k % 7 - 3);
    float dlw = (float)(xq - nx) * (2.f / 55.f);
    float dlh = (float)(yy - ny) * (2.f / 55.f);
    float v16 = wp00 * dlw + wp01 * dlh;
    float v17 = wp10 * dlw + wp11 * dlh;
    ps[0] += v16; ps[1] += v16 * v16;
    ps[2] += v17; ps[3] += v17 * v17;
  }
  #pragma unroll
  for (int i = 0; i < 4; i++) {
    #pragma unroll
    for (int off = 1; off <= 32; off <<= 1)
      ps[i] += __shfl_xor(ps[i], off);
  }
  if (lane == 0) {
    #pragma unroll
    for (int i = 0; i < 4; i++) pred[wv][i] = ps[i];
  }
  __syncthreads();

  if (tid < 80) {
    int cq2 = tid / 20, v = tid % 20;
    float t = red[0][cq2][v] + red[1][cq2][v] + red[2][cq2][v] + red[3][cq2][v];
    int c = cq2 * 4 + v / 5, qty = v % 5;
    atomicAdd(&parts[c * 5 + qty], t);
  } else if (tid < 84) {
    int i = tid - 80;
    float t = pred[0][i] + pred[1][i] + pred[2][i] + pred[3][i];
    atomicAdd(&parts[80 + i], 2.0f * t);   // x2 for the two n
  }
}

// ---------------------------------------------------------------------------
// Kernel 2c: combine parts -> gsum1[36].
// ---------------------------------------------------------------------------
__global__ void k_comb(const float* __restrict__ parts, float* __restrict__ gsum1)
{
  int tid = threadIdx.x;
  if (tid < 16) {
    const float* P = parts + tid * 5;
    gsum1[tid]      = 49.f * P[0] - P[3];
    gsum1[18 + tid] = 49.f * P[1] - 2.f * P[2] + P[4];
  } else if (tid == 16) {
    gsum1[16] = parts[80]; gsum1[17] = parts[82];
    gsum1[34] = parts[81]; gsum1[35] = parts[83];
  }
}

// ---------------------------------------------------------------------------
// Kernel 3: BN2 statistics (16 channels), 784 blocks + atomics.
// ---------------------------------------------------------------------------
__global__ __launch_bounds__(256) void k_stats2(
    const float* __restrict__ x1t, const float* __restrict__ x2t,
    const float* __restrict__ small,
    const float* __restrict__ gsum1, float* __restrict__ gsum2)
{
  __shared__ float red[4][32];
  const int tid = threadIdx.x;
  const float inv = 1.f / NKQ;
  float sc1r[18], sh1r[18];
  #pragma unroll
  for (int c = 0; c < 18; c++) {
    float m = gsum1[c] * inv;
    float var = gsum1[18 + c] * inv - m * m;
    float sc = small[S_G1 + c] * rsqrtf(var + 1e-5f);
    sc1r[c] = sc; sh1r[c] = small[S_BE1 + c] - m * sc;
  }

  const int bid = blockIdx.x;              // 784 = 2n * 49k * 8
  const int n = bid / 392;
  const int r = bid % 392;
  const int k = r >> 3, eig = r & 7;
  const int ki = k / 7 - 3, kj = k % 7 - 3;
  const float wp00 = small[S_WP+0], wp01 = small[S_WP+1];
  const float wp10 = small[S_WP+2], wp11 = small[S_WP+3];
  const float* cw1f = small + S_CW1;
  float s[16], ss[16];
  #pragma unroll
  for (int i = 0; i < 16; i++) { s[i] = 0.f; ss[i] = 0.f; }

  for (int qq = tid; qq < 392; qq += 256) {
    int q = eig * 392 + qq;
    int y = q / WID, xx = q - y * WID;
    int ny = refl(y + ki), nx = refl(xx + kj);
    int nb = ny * WID + nx;
    float t1v[18];
    const float4* a4 = (const float4*)(x1t + (size_t)(n * HWS + q) * 16);
    const float4* b4 = (const float4*)(x2t + (size_t)(n * HWS + nb) * 16);
    #pragma unroll
    for (int r4 = 0; r4 < 4; r4++) {
      float4 av = a4[r4], bv = b4[r4];
      t1v[r4*4+0] = av.x - bv.x; t1v[r4*4+1] = av.y - bv.y;
      t1v[r4*4+2] = av.z - bv.z; t1v[r4*4+3] = av.w - bv.w;
    }
    float dlw = (float)(xx - nx) * (2.f / 55.f);
    float dlh = (float)(y - ny) * (2.f / 55.f);
    t1v[16] = wp00 * dlw + wp01 * dlh;
    t1v[17] = wp10 * dlw + wp11 * dlh;
    #pragma unroll
    for (int c = 0; c < 18; c++) t1v[c] = fmaxf(fmaf(t1v[c], sc1r[c], sh1r[c]), 0.f);
    #pragma unroll
    for (int r2 = 0; r2 < 16; r2++) {
      float acc = 0.f;
      #pragma unroll
      for (int c = 0; c < 18; c++) acc = fmaf(cw1f[r2 * 18 + c], t1v[c], acc);
      s[r2] += acc; ss[r2] += acc * acc;
    }
  }

  #pragma unroll
  for (int i = 0; i < 16; i++) {
    #pragma unroll
    for (int off = 32; off > 0; off >>= 1) {
      s[i]  += __shfl_down(s[i], off);
      ss[i] += __shfl_down(ss[i], off);
    }
  }
  const int wvv = tid >> 6, lane = tid & 63;
  if (lane == 0) {
    #pragma unroll
    for (int i = 0; i < 16; i++) { red[wvv][i] = s[i]; red[wvv][16 + i] = ss[i]; }
  }
  __syncthreads();
  if (tid < 32) {
    float t = red[0][tid] + red[1][tid] + red[2][tid] + red[3][tid];
    atomicAdd(&gsum2[tid], t);
  }
}

// ---------------------------------------------------------------------------
// Kernel 4: 4 waves/block, one wave per pixel. Deferred-normalization
// softmax (half e in LDS); lane owns channels 4l..4l+3 (one group g = l>>1)
// -> one coalesced int2 x3 load per k.
// ---------------------------------------------------------------------------
__global__ __launch_bounds__(256) void k_final(
    const float* __restrict__ x1t, const float* __restrict__ x2t,
    const short* __restrict__ x3i, const float* __restrict__ small,
    const float* __restrict__ gsum1, const float* __restrict__ gsum2,
    float* __restrict__ outf)
{
  __shared__ __half wwh[4][49][34];
  __shared__ int nbs[4][49];
  __shared__ float sc1s[18], sh1s[18], sc2s[16], sh2s[16];

  const int tid = threadIdx.x;
  const int lane = tid & 63;
  const int wv = tid >> 6;
  const float inv = 1.f / NKQ;

  if (tid < 18) {
    float m = gsum1[tid] * inv;
    float var = gsum1[18 + tid] * inv - m * m;
    float sc = small[S_G1 + tid] * rsqrtf(var + 1e-5f);
    sc1s[tid] = sc; sh1s[tid] = small[S_BE1 + tid] - m * sc;
  } else if (tid >= 32 && tid < 48) {
    int c = tid - 32;
    float m = gsum2[c] * inv;
    float var = gsum2[16 + c] * inv - m * m;
    float sc = small[S_G2 + c] * rsqrtf(var + 1e-5f);
    sc2s[c] = sc; sh2s[c] = small[S_BE2 + c] - m * sc;
  }
  __syncthreads();

  const int P = blockIdx.x * 4 + wv;   // grid = 1568
  const int n = P / HWS, q = P % HWS;
  const int y = q / WID, xx = q - y * WID;

  const bool valid = lane < 49;
  const int kk = valid ? lane : 48;
  const int ki = kk / 7 - 3, kj = kk % 7 - 3;
  const int ny = refl(y + ki), nx = refl(xx + kj);
  const int nb = ny * WID + nx;
  if (valid) nbs[wv][lane] = nb;

  float t1v[18];
  {
    const float4* a4 = (const float4*)(x1t + (size_t)(n * HWS + q) * 16);
    const float4* b4 = (const float4*)(x2t + (size_t)(n * HWS + nb) * 16);
    #pragma unroll
    for (int r4 = 0; r4 < 4; r4++) {
      float4 av = a4[r4], bv = b4[r4];
      t1v[r4*4+0] = av.x - bv.x; t1v[r4*4+1] = av.y - bv.y;
      t1v[r4*4+2] = av.z - bv.z; t1v[r4*4+3] = av.w - bv.w;
    }
    float dlw = (float)(xx - nx) * (2.f / 55.f);
    float dlh = (float)(y - ny) * (2.f / 55.f);
    t1v[16] = small[S_WP+0] * dlw + small[S_WP+1] * dlh;
    t1v[17] = small[S_WP+2] * dlw + small[S_WP+3] * dlh;
  }
  #pragma unroll
  for (int c = 0; c < 18; c++)
    t1v[c] = fmaxf(fmaf(t1v[c], sc1s[c], sh1s[c]), 0.f);

  float t2v[16];
  #pragma unroll
  for (int r = 0; r < 16; r++) {
    float acc = 0.f;
    #pragma unroll
    for (int c = 0; c < 18; c++) acc = fmaf(small[S_CW1 + r * 18 + c], t1v[c], acc);
    t2v[r] = fmaxf(fmaf(acc, sc2s[r], sh2s[r]), 0.f);
  }

  #pragma unroll
  for (int g2 = 0; g2 < 32; g2++) {
    float acc = small[S_CB2 + g2];
    #pragma unroll
    for (int r = 0; r < 16; r++) acc = fmaf(small[S_CW2 + g2 * 16 + r], t2v[r], acc);
    if (valid) wwh[wv][lane][g2] = __float2half(__expf(acc));
  }
  __syncthreads();

  const short* x3p = x3i + (size_t)n * HWS * 256;
  const int* nbp = nbs[wv];
  const __half (*wh)[34] = wwh[wv];
  const int g = lane >> 1;
  const int o0 = lane * 4;
  float acc0 = 0.f, acc1 = 0.f, acc2 = 0.f, acc3 = 0.f, wsum = 0.f;
  #pragma unroll 7
  for (int k = 0; k < 49; k++) {
    const int2 d = *(const int2*)(x3p + (size_t)nbp[k] * 256 + o0);
    float w = __half2float(wh[k][g]);
    wsum += w;
    acc0 = fmaf(w, (float)(short)(d.x & 0xffff), acc0);
    acc1 = fmaf(w, (float)(short)(d.x >> 16),    acc1);
    acc2 = fmaf(w, (float)(short)(d.y & 0xffff), acc2);
    acc3 = fmaf(w, (float)(short)(d.y >> 16),    acc3);
  }
  const float sc = X3INV / wsum;
  const size_t ob = (size_t)(n * 256 + o0) * HWS + q;
  outf[ob]           = acc0 * sc;
  outf[ob + HWS]     = acc1 * sc;
  outf[ob + 2 * HWS] = acc2 * sc;
  outf[ob + 3 * HWS] = acc3 * sc;
}

// ---------------------------------------------------------------------------
extern "C" void kernel_launch(void* const* d_in, const int* in_sizes, int n_in,
                              void* d_out, int out_size, void* d_ws, size_t ws_size,
                              hipStream_t stream) {
  (void)in_sizes; (void)n_in; (void)out_size; (void)ws_size;
  char* ws = (char*)d_ws;
  float* gsum1 = (float*)(ws + 0);       // 36 f32
  float* gsum2 = (float*)(ws + 160);     // 32 f32
  float* parts = (float*)(ws + 320);     // 84 f32 (ends 656)
  float* small = (float*)(ws + 704);     // S_TOT f32 (ends 4320)
  float* x1t   = (float*)(ws + 4608);    // 2*3136*16 f32
  float* x2t   = (float*)(ws + 406016);  // 2*3136*16 f32
  short* x3i   = (short*)(ws + 807424);  // 2*3136*256 i16 (ends 4018688)
  float* outf  = (float*)d_out;
  float* wT    = (float*)d_out;                  // scratch (overwritten later)
  float* Rbox  = (float*)d_out + 262144;         // 6272*16 f32 box-sum scratch

  const float* x   = (const float*)d_in[0];
  const float* w1  = (const float*)d_in[1];
  const float* b1  = (const float*)d_in[2];
  const float* w2  = (const float*)d_in[3];
  const float* b2  = (const float*)d_in[4];
  const float* w3  = (const float*)d_in[5];
  const float* b3  = (const float*)d_in[6];
  const float* wp  = (const float*)d_in[7];
  const float* g1  = (const float*)d_in[9];
  const float* be1 = (const float*)d_in[10];
  const float* cw1 = (const float*)d_in[11];
  const float* g2  = (const float*)d_in[12];
  const float* be2 = (const float*)d_in[13];
  const float* cw2 = (const float*)d_in[14];
  const float* cb2 = (const float*)d_in[15];

  hipMemsetAsync(d_ws, 0, 704, stream);  // zero gsum1/gsum2/parts
  k_prep<<<292, 256, 0, stream>>>(w1, w2, w3, cw1, cw2, cb2, wp,
                                  g1, be1, g2, be2, small, wT);
  k_proj<<<1664, 64, 0, stream>>>(x, wT, b1, b2, b3, x1t, x2t, x3i);
  k_rowbox<<<98, 256, 0, stream>>>(x2t, Rbox);
  k_bn1<<<98, 256, 0, stream>>>(x1t, x2t, Rbox, small, parts);
  k_comb<<<1, 64, 0, stream>>>(parts, gsum1);
  k_stats2<<<784, 256, 0, stream>>>(x1t, x2t, small, gsum1, gsum2);
  k_final<<<1568, 256, 0, stream>>>(x1t, x2t, x3i, small, gsum1, gsum2, outf);
}

// Round 17
// 186.440 us; speedup vs baseline: 1.0702x; 1.0702x over previous
//
#include <hip/hip_runtime.h>
#include <hip/hip_bf16.h>
#include <hip/hip_fp16.h>
#include <cstdint>

#define HWS 3136
#define WID 56
#define NKQ 307328.0f   // 2 * 49 * 3136
#define X3SCALE 2048.0f
#define X3INV   (1.0f / 2048.0f)

// f32 parameter block ("small", at ws byte offset 704), element offsets:
#define S_CW1 0      // 288  (16x18)
#define S_CW2 288    // 512  (32x16)
#define S_CB2 800    // 32
#define S_WP  832    // 4
#define S_G1  836    // 18
#define S_BE1 854    // 18
#define S_G2  872    // 16
#define S_BE2 888    // 16
#define S_TOT 904
#define NWT   73728  // 256*288 transposed weights

__device__ __forceinline__ int refl(int i) {
  if (i < 0) i = -i;
  if (i >= WID) i = 2 * WID - 2 - i;
  return i;
}

// ---------------------------------------------------------------------------
// Kernel 0: pack small params + build wT[c][288] in d_out scratch.
// ---------------------------------------------------------------------------
__global__ __launch_bounds__(256) void k_prep(
    const float* __restrict__ w1, const float* __restrict__ w2,
    const float* __restrict__ w3,
    const float* __restrict__ cw1, const float* __restrict__ cw2,
    const float* __restrict__ cb2, const float* __restrict__ wp,
    const float* __restrict__ g1, const float* __restrict__ be1,
    const float* __restrict__ g2, const float* __restrict__ be2,
    float* __restrict__ small, float* __restrict__ wT)
{
  int e = blockIdx.x * 256 + threadIdx.x;
  if (e < S_TOT) {
    float v;
    if (e < S_CW2)      v = cw1[e];
    else if (e < S_CB2) v = cw2[e - S_CW2];
    else if (e < S_WP)  v = cb2[e - S_CB2];
    else if (e < S_G1)  v = wp [e - S_WP];
    else if (e < S_BE1) v = g1 [e - S_G1];
    else if (e < S_G2)  v = be1[e - S_BE1];
    else if (e < S_BE2) v = g2 [e - S_G2];
    else                v = be2[e - S_BE2];
    small[e] = v;
  }
  int et = e - S_TOT;
  if (et >= 0 && et < NWT) {
    int c = et / 288, r = et - (et / 288) * 288;
    float v = (r < 16) ? w1[r * 256 + c]
            : (r < 32) ? w2[(r - 16) * 256 + c]
                       : w3[(r - 32) * 256 + c];
    wT[et] = v;   // wT[c*288 + r]
  }
}

// ---------------------------------------------------------------------------
// Kernel 1: lane = pixel, 6 rows/thread via wave-uniform scalar weight loads.
// 48 row-chunks per pixel-chunk -> 4704 work-waves (4.6/SIMD) for latency
// hiding. XCD swizzle keeps all 48 chunks of a pixel-chunk on one XCD.
// grid = 8 * 13 * 48 = 4992 (pad blocks exit).
// ---------------------------------------------------------------------------
__global__ __launch_bounds__(64) void k_proj(
    const float* __restrict__ x, const float* __restrict__ wT,
    const float* __restrict__ b1, const float* __restrict__ b2,
    const float* __restrict__ b3,
    float* __restrict__ x1t, float* __restrict__ x2t, short* __restrict__ x3i)
{
  const int bid = blockIdx.x;
  const int c8 = bid & 7;
  const int t8 = bid >> 3;
  const int rc = t8 % 48;
  const int pck = (t8 / 48) * 8 + c8;
  if (pck >= 98) return;

  const int lane = threadIdx.x;
  const int r0 = rc * 6;
  const int P = pck * 64 + lane;
  const int n = P / HWS;

  float acc[6];
  #pragma unroll
  for (int i = 0; i < 6; i++) {
    int r = r0 + i;
    acc[i] = (r < 16) ? b1[r] : (r < 32) ? b2[r - 16] : b3[r - 32];
  }

  const float* xc = x + (size_t)n * 256 * HWS + (P - n * HWS);
  const float* wt0 = wT + r0;
  #pragma unroll 16
  for (int c = 0; c < 256; c++) {
    float xv = xc[(size_t)c * HWS];
    const float* wt = wt0 + c * 288;
    #pragma unroll
    for (int i = 0; i < 6; i++)
      acc[i] = fmaf(wt[i], xv, acc[i]);
  }

  #pragma unroll
  for (int i = 0; i < 6; i++) {
    int r = r0 + i;
    if (r < 16)
      x1t[(size_t)P * 16 + r] = acc[i];
    else if (r < 32)
      x2t[(size_t)P * 16 + (r - 16)] = acc[i];
    else {
      float cl = fminf(fmaxf(acc[i], -15.9f), 15.9f);
      x3i[(size_t)P * 256 + (r - 32)] = (short)__float2int_rn(cl * X3SCALE);
    }
  }
}

// ---------------------------------------------------------------------------
// Kernel 2a: row-pass 7-tap reflect box-sum of x2t -> R[p][16] (d_out scratch)
// ---------------------------------------------------------------------------
__global__ __launch_bounds__(256) void k_rowbox(
    const float* __restrict__ x2t, float* __restrict__ R)
{
  int idx = blockIdx.x * 256 + threadIdx.x;   // 98*256 = 6272*4
  int p = idx >> 2, cq = (idx & 3) * 4;
  int n = p / HWS, q = p % HWS;
  int y = q / WID, xx = q - y * WID;
  float4 s = {0.f, 0.f, 0.f, 0.f};
  #pragma unroll
  for (int d = -3; d <= 3; d++) {
    int nx = refl(xx + d);
    float4 v = *(const float4*)(x2t + (size_t)(n * HWS + y * WID + nx) * 16 + cq);
    s.x += v.x; s.y += v.y; s.z += v.z; s.w += v.w;
  }
  *(float4*)(R + (size_t)p * 16 + cq) = s;
}

// ---------------------------------------------------------------------------
// Kernel 2b: closed-form BN1 stat parts.
// ---------------------------------------------------------------------------
__global__ __launch_bounds__(256) void k_bn1(
    const float* __restrict__ x1t, const float* __restrict__ x2t,
    const float* __restrict__ R, const float* __restrict__ small,
    float* __restrict__ parts)
{
  __shared__ float cxs[56];
  __shared__ float red[4][4][20];
  __shared__ float pred[4][4];
  const int tid = threadIdx.x;
  if (tid < 56) {
    int cnt = 0;
    for (int xx = 0; xx < 56; xx++)
      for (int d = -3; d <= 3; d++)
        if (refl(xx + d) == tid) cnt++;
    cxs[tid] = (float)cnt;
  }
  __syncthreads();

  const int idx = blockIdx.x * 256 + tid;     // 98*256 = 6272*4
  const int p = idx >> 2, cq = (idx & 3) * 4;
  const int n = p / HWS, q = p % HWS;
  const int y = q / WID, xx = q - y * WID;

  float4 x1v = *(const float4*)(x1t + (size_t)p * 16 + cq);
  float4 x2v = *(const float4*)(x2t + (size_t)p * 16 + cq);
  float4 b2 = {0.f, 0.f, 0.f, 0.f};
  #pragma unroll
  for (int d = -3; d <= 3; d++) {
    int ny = refl(y + d);
    float4 v = *(const float4*)(R + (size_t)(n * HWS + ny * WID + xx) * 16 + cq);
    b2.x += v.x; b2.y += v.y; b2.z += v.z; b2.w += v.w;
  }
  float cnt = cxs[y] * cxs[xx];

  float a[20];
  {
    float xv[4] = {x1v.x, x1v.y, x1v.z, x1v.w};
    float x2a[4] = {x2v.x, x2v.y, x2v.z, x2v.w};
    float bb[4] = {b2.x, b2.y, b2.z, b2.w};
    #pragma unroll
    for (int j = 0; j < 4; j++) {
      a[j*5+0] = xv[j];
      a[j*5+1] = xv[j] * xv[j];
      a[j*5+2] = xv[j] * bb[j];
      a[j*5+3] = cnt * x2a[j];
      a[j*5+4] = cnt * x2a[j] * x2a[j];
    }
  }
  #pragma unroll
  for (int i = 0; i < 20; i++) {
    #pragma unroll
    for (int off = 4; off <= 32; off <<= 1)
      a[i] += __shfl_xor(a[i], off);
  }
  const int lane = tid & 63, wv = tid >> 6;
  if (lane < 4) {
    #pragma unroll
    for (int i = 0; i < 20; i++) red[wv][lane][i] = a[i];
  }

  float ps[4] = {0.f, 0.f, 0.f, 0.f};
  const float wp00 = small[S_WP+0], wp01 = small[S_WP+1];
  const float wp10 = small[S_WP+2], wp11 = small[S_WP+3];
  for (int it = idx; it < 153664; it += 25088) {
    int k = it / 3136, qq = it - (it / 3136) * 3136;
    int yy = qq / WID, xq = qq - yy * WID;
    int ny = refl(yy + k / 7 - 3), nx = refl(xq + k % 7 - 3);
    float dlw = (float)(xq - nx) * (2.f / 55.f);
    float dlh = (float)(yy - ny) * (2.f / 55.f);
    float v16 = wp00 * dlw + wp01 * dlh;
    float v17 = wp10 * dlw + wp11 * dlh;
    ps[0] += v16; ps[1] += v16 * v16;
    ps[2] += v17; ps[3] += v17 * v17;
  }
  #pragma unroll
  for (int i = 0; i < 4; i++) {
    #pragma unroll
    for (int off = 1; off <= 32; off <<= 1)
      ps[i] += __shfl_xor(ps[i], off);
  }
  if (lane == 0) {
    #pragma unroll
    for (int i = 0; i < 4; i++) pred[wv][i] = ps[i];
  }
  __syncthreads();

  if (tid < 80) {
    int cq2 = tid / 20, v = tid % 20;
    float t = red[0][cq2][v] + red[1][cq2][v] + red[2][cq2][v] + red[3][cq2][v];
    int c = cq2 * 4 + v / 5, qty = v % 5;
    atomicAdd(&parts[c * 5 + qty], t);
  } else if (tid < 84) {
    int i = tid - 80;
    float t = pred[0][i] + pred[1][i] + pred[2][i] + pred[3][i];
    atomicAdd(&parts[80 + i], 2.0f * t);   // x2 for the two n
  }
}

// ---------------------------------------------------------------------------
// Kernel 2c: combine parts -> gsum1[36].
// ---------------------------------------------------------------------------
__global__ void k_comb(const float* __restrict__ parts, float* __restrict__ gsum1)
{
  int tid = threadIdx.x;
  if (tid < 16) {
    const float* P = parts + tid * 5;
    gsum1[tid]      = 49.f * P[0] - P[3];
    gsum1[18 + tid] = 49.f * P[1] - 2.f * P[2] + P[4];
  } else if (tid == 16) {
    gsum1[16] = parts[80]; gsum1[17] = parts[82];
    gsum1[34] = parts[81]; gsum1[35] = parts[83];
  }
}

// ---------------------------------------------------------------------------
// Kernel 3: BN2 statistics (16 channels), 784 blocks + atomics.
// ---------------------------------------------------------------------------
__global__ __launch_bounds__(256) void k_stats2(
    const float* __restrict__ x1t, const float* __restrict__ x2t,
    const float* __restrict__ small,
    const float* __restrict__ gsum1, float* __restrict__ gsum2)
{
  __shared__ float red[4][32];
  const int tid = threadIdx.x;
  const float inv = 1.f / NKQ;
  float sc1r[18], sh1r[18];
  #pragma unroll
  for (int c = 0; c < 18; c++) {
    float m = gsum1[c] * inv;
    float var = gsum1[18 + c] * inv - m * m;
    float sc = small[S_G1 + c] * rsqrtf(var + 1e-5f);
    sc1r[c] = sc; sh1r[c] = small[S_BE1 + c] - m * sc;
  }

  const int bid = blockIdx.x;              // 784 = 2n * 49k * 8
  const int n = bid / 392;
  const int r = bid % 392;
  const int k = r >> 3, eig = r & 7;
  const int ki = k / 7 - 3, kj = k % 7 - 3;
  const float wp00 = small[S_WP+0], wp01 = small[S_WP+1];
  const float wp10 = small[S_WP+2], wp11 = small[S_WP+3];
  const float* cw1f = small + S_CW1;
  float s[16], ss[16];
  #pragma unroll
  for (int i = 0; i < 16; i++) { s[i] = 0.f; ss[i] = 0.f; }

  for (int qq = tid; qq < 392; qq += 256) {
    int q = eig * 392 + qq;
    int y = q / WID, xx = q - y * WID;
    int ny = refl(y + ki), nx = refl(xx + kj);
    int nb = ny * WID + nx;
    float t1v[18];
    const float4* a4 = (const float4*)(x1t + (size_t)(n * HWS + q) * 16);
    const float4* b4 = (const float4*)(x2t + (size_t)(n * HWS + nb) * 16);
    #pragma unroll
    for (int r4 = 0; r4 < 4; r4++) {
      float4 av = a4[r4], bv = b4[r4];
      t1v[r4*4+0] = av.x - bv.x; t1v[r4*4+1] = av.y - bv.y;
      t1v[r4*4+2] = av.z - bv.z; t1v[r4*4+3] = av.w - bv.w;
    }
    float dlw = (float)(xx - nx) * (2.f / 55.f);
    float dlh = (float)(y - ny) * (2.f / 55.f);
    t1v[16] = wp00 * dlw + wp01 * dlh;
    t1v[17] = wp10 * dlw + wp11 * dlh;
    #pragma unroll
    for (int c = 0; c < 18; c++) t1v[c] = fmaxf(fmaf(t1v[c], sc1r[c], sh1r[c]), 0.f);
    #pragma unroll
    for (int r2 = 0; r2 < 16; r2++) {
      float acc = 0.f;
      #pragma unroll
      for (int c = 0; c < 18; c++) acc = fmaf(cw1f[r2 * 18 + c], t1v[c], acc);
      s[r2] += acc; ss[r2] += acc * acc;
    }
  }

  #pragma unroll
  for (int i = 0; i < 16; i++) {
    #pragma unroll
    for (int off = 32; off > 0; off >>= 1) {
      s[i]  += __shfl_down(s[i], off);
      ss[i] += __shfl_down(ss[i], off);
    }
  }
  const int wvv = tid >> 6, lane = tid & 63;
  if (lane == 0) {
    #pragma unroll
    for (int i = 0; i < 16; i++) { red[wvv][i] = s[i]; red[wvv][16 + i] = ss[i]; }
  }
  __syncthreads();
  if (tid < 32) {
    float t = red[0][tid] + red[1][tid] + red[2][tid] + red[3][tid];
    atomicAdd(&gsum2[tid], t);
  }
}

// ---------------------------------------------------------------------------
// Kernel 4: 4 waves/block, one wave per pixel. Deferred-normalization
// softmax (half e in LDS); lane owns channels 4l..4l+3 (one group g = l>>1)
// -> one coalesced int2 x3 load per k.
// ---------------------------------------------------------------------------
__global__ __launch_bounds__(256) void k_final(
    const float* __restrict__ x1t, const float* __restrict__ x2t,
    const short* __restrict__ x3i, const float* __restrict__ small,
    const float* __restrict__ gsum1, const float* __restrict__ gsum2,
    float* __restrict__ outf)
{
  __shared__ __half wwh[4][49][34];
  __shared__ int nbs[4][49];
  __shared__ float sc1s[18], sh1s[18], sc2s[16], sh2s[16];

  const int tid = threadIdx.x;
  const int lane = tid & 63;
  const int wv = tid >> 6;
  const float inv = 1.f / NKQ;

  if (tid < 18) {
    float m = gsum1[tid] * inv;
    float var = gsum1[18 + tid] * inv - m * m;
    float sc = small[S_G1 + tid] * rsqrtf(var + 1e-5f);
    sc1s[tid] = sc; sh1s[tid] = small[S_BE1 + tid] - m * sc;
  } else if (tid >= 32 && tid < 48) {
    int c = tid - 32;
    float m = gsum2[c] * inv;
    float var = gsum2[16 + c] * inv - m * m;
    float sc = small[S_G2 + c] * rsqrtf(var + 1e-5f);
    sc2s[c] = sc; sh2s[c] = small[S_BE2 + c] - m * sc;
  }
  __syncthreads();

  const int P = blockIdx.x * 4 + wv;   // grid = 1568
  const int n = P / HWS, q = P % HWS;
  const int y = q / WID, xx = q - y * WID;

  const bool valid = lane < 49;
  const int kk = valid ? lane : 48;
  const int ki = kk / 7 - 3, kj = kk % 7 - 3;
  const int ny = refl(y + ki), nx = refl(xx + kj);
  const int nb = ny * WID + nx;
  if (valid) nbs[wv][lane] = nb;

  float t1v[18];
  {
    const float4* a4 = (const float4*)(x1t + (size_t)(n * HWS + q) * 16);
    const float4* b4 = (const float4*)(x2t + (size_t)(n * HWS + nb) * 16);
    #pragma unroll
    for (int r4 = 0; r4 < 4; r4++) {
      float4 av = a4[r4], bv = b4[r4];
      t1v[r4*4+0] = av.x - bv.x; t1v[r4*4+1] = av.y - bv.y;
      t1v[r4*4+2] = av.z - bv.z; t1v[r4*4+3] = av.w - bv.w;
    }
    float dlw = (float)(xx - nx) * (2.f / 55.f);
    float dlh = (float)(y - ny) * (2.f / 55.f);
    t1v[16] = small[S_WP+0] * dlw + small[S_WP+1] * dlh;
    t1v[17] = small[S_WP+2] * dlw + small[S_WP+3] * dlh;
  }
  #pragma unroll
  for (int c = 0; c < 18; c++)
    t1v[c] = fmaxf(fmaf(t1v[c], sc1s[c], sh1s[c]), 0.f);

  float t2v[16];
  #pragma unroll
  for (int r = 0; r < 16; r++) {
    float acc = 0.f;
    #pragma unroll
    for (int c = 0; c < 18; c++) acc = fmaf(small[S_CW1 + r * 18 + c], t1v[c], acc);
    t2v[r] = fmaxf(fmaf(acc, sc2s[r], sh2s[r]), 0.f);
  }

  #pragma unroll
  for (int g2 = 0; g2 < 32; g2++) {
    float acc = small[S_CB2 + g2];
    #pragma unroll
    for (int r = 0; r < 16; r++) acc = fmaf(small[S_CW2 + g2 * 16 + r], t2v[r], acc);
    if (valid) wwh[wv][lane][g2] = __float2half(__expf(acc));
  }
  __syncthreads();

  const short* x3p = x3i + (size_t)n * HWS * 256;
  const int* nbp = nbs[wv];
  const __half (*wh)[34] = wwh[wv];
  const int g = lane >> 1;
  const int o0 = lane * 4;
  float acc0 = 0.f, acc1 = 0.f, acc2 = 0.f, acc3 = 0.f, wsum = 0.f;
  #pragma unroll 7
  for (int k = 0; k < 49; k++) {
    const int2 d = *(const int2*)(x3p + (size_t)nbp[k] * 256 + o0);
    float w = __half2float(wh[k][g]);
    wsum += w;
    acc0 = fmaf(w, (float)(short)(d.x & 0xffff), acc0);
    acc1 = fmaf(w, (float)(short)(d.x >> 16),    acc1);
    acc2 = fmaf(w, (float)(short)(d.y & 0xffff), acc2);
    acc3 = fmaf(w, (float)(short)(d.y >> 16),    acc3);
  }
  const float sc = X3INV / wsum;
  const size_t ob = (size_t)(n * 256 + o0) * HWS + q;
  outf[ob]           = acc0 * sc;
  outf[ob + HWS]     = acc1 * sc;
  outf[ob + 2 * HWS] = acc2 * sc;
  outf[ob + 3 * HWS] = acc3 * sc;
}

// ---------------------------------------------------------------------------
extern "C" void kernel_launch(void* const* d_in, const int* in_sizes, int n_in,
                              void* d_out, int out_size, void* d_ws, size_t ws_size,
                              hipStream_t stream) {
  (void)in_sizes; (void)n_in; (void)out_size; (void)ws_size;
  char* ws = (char*)d_ws;
  float* gsum1 = (float*)(ws + 0);       // 36 f32
  float* gsum2 = (float*)(ws + 160);     // 32 f32
  float* parts = (float*)(ws + 320);     // 84 f32 (ends 656)
  float* small = (float*)(ws + 704);     // S_TOT f32 (ends 4320)
  float* x1t   = (float*)(ws + 4608);    // 2*3136*16 f32
  float* x2t   = (float*)(ws + 406016);  // 2*3136*16 f32
  short* x3i   = (short*)(ws + 807424);  // 2*3136*256 i16 (ends 4018688)
  float* outf  = (float*)d_out;
  float* wT    = (float*)d_out;                  // scratch (overwritten later)
  float* Rbox  = (float*)d_out + 262144;         // 6272*16 f32 box-sum scratch

  const float* x   = (const float*)d_in[0];
  const float* w1  = (const float*)d_in[1];
  const float* b1  = (const float*)d_in[2];
  const float* w2  = (const float*)d_in[3];
  const float* b2  = (const float*)d_in[4];
  const float* w3  = (const float*)d_in[5];
  const float* b3  = (const float*)d_in[6];
  const float* wp  = (const float*)d_in[7];
  const float* g1  = (const float*)d_in[9];
  const float* be1 = (const float*)d_in[10];
  const float* cw1 = (const float*)d_in[11];
  const float* g2  = (const float*)d_in[12];
  const float* be2 = (const float*)d_in[13];
  const float* cw2 = (const float*)d_in[14];
  const float* cb2 = (const float*)d_in[15];

  hipMemsetAsync(d_ws, 0, 704, stream);  // zero gsum1/gsum2/parts
  k_prep<<<292, 256, 0, stream>>>(w1, w2, w3, cw1, cw2, cb2, wp,
                                  g1, be1, g2, be2, small, wT);
  k_proj<<<4992, 64, 0, stream>>>(x, wT, b1, b2, b3, x1t, x2t, x3i);
  k_rowbox<<<98, 256, 0, stream>>>(x2t, Rbox);
  k_bn1<<<98, 256, 0, stream>>>(x1t, x2t, Rbox, small, parts);
  k_comb<<<1, 64, 0, stream>>>(parts, gsum1);
  k_stats2<<<784, 256, 0, stream>>>(x1t, x2t, small, gsum1, gsum2);
  k_final<<<1568, 256, 0, stream>>>(x1t, x2t, x3i, small, gsum1, gsum2, outf);
}

// Round 18
// 182.598 us; speedup vs baseline: 1.0927x; 1.0210x over previous
//
#include <hip/hip_runtime.h>
#include <hip/hip_bf16.h>
#include <hip/hip_fp16.h>
#include <cstdint>

#define HWS 3136
#define WID 56
#define NKQ 307328.0f   // 2 * 49 * 3136
#define X3SCALE 2048.0f
#define X3INV   (1.0f / 2048.0f)

// f32 parameter block ("small", at ws byte offset 704), element offsets:
#define S_CW1 0      // 288  (16x18)
#define S_CW2 288    // 512  (32x16)
#define S_CB2 800    // 32
#define S_WP  832    // 4
#define S_G1  836    // 18
#define S_BE1 854    // 18
#define S_G2  872    // 16
#define S_BE2 888    // 16
#define S_TOT 904
#define NWT   73728  // 256*288 transposed weights

__device__ __forceinline__ int refl(int i) {
  if (i < 0) i = -i;
  if (i >= WID) i = 2 * WID - 2 - i;
  return i;
}

// ---------------------------------------------------------------------------
// Kernel 0: pack small params + build wT[c][288] in d_out scratch.
// Block 0 also zeroes the accumulator region (parts/gsum1/gsum2).
// ---------------------------------------------------------------------------
__global__ __launch_bounds__(256) void k_prep(
    const float* __restrict__ w1, const float* __restrict__ w2,
    const float* __restrict__ w3,
    const float* __restrict__ cw1, const float* __restrict__ cw2,
    const float* __restrict__ cb2, const float* __restrict__ wp,
    const float* __restrict__ g1, const float* __restrict__ be1,
    const float* __restrict__ g2, const float* __restrict__ be2,
    float* __restrict__ small, float* __restrict__ wT,
    float* __restrict__ gbase)
{
  if (blockIdx.x == 0 && threadIdx.x < 176) gbase[threadIdx.x] = 0.f;

  int e = blockIdx.x * 256 + threadIdx.x;
  if (e < S_TOT) {
    float v;
    if (e < S_CW2)      v = cw1[e];
    else if (e < S_CB2) v = cw2[e - S_CW2];
    else if (e < S_WP)  v = cb2[e - S_CB2];
    else if (e < S_G1)  v = wp [e - S_WP];
    else if (e < S_BE1) v = g1 [e - S_G1];
    else if (e < S_G2)  v = be1[e - S_BE1];
    else if (e < S_BE2) v = g2 [e - S_G2];
    else                v = be2[e - S_BE2];
    small[e] = v;
  }
  int et = e - S_TOT;
  if (et >= 0 && et < NWT) {
    int c = et / 288, r = et - (et / 288) * 288;
    float v = (r < 16) ? w1[r * 256 + c]
            : (r < 32) ? w2[(r - 16) * 256 + c]
                       : w3[(r - 32) * 256 + c];
    wT[et] = v;   // wT[c*288 + r]
  }
}

// ---------------------------------------------------------------------------
// Kernel 1: lane = pixel, 6 rows/thread via wave-uniform scalar weight loads.
// 48 row-chunks per pixel-chunk -> 4704 work-waves (4.6/SIMD). XCD swizzle
// keeps all 48 chunks of a pixel-chunk on one XCD. grid = 8*13*48 = 4992.
// ---------------------------------------------------------------------------
__global__ __launch_bounds__(64) void k_proj(
    const float* __restrict__ x, const float* __restrict__ wT,
    const float* __restrict__ b1, const float* __restrict__ b2,
    const float* __restrict__ b3,
    float* __restrict__ x1t, float* __restrict__ x2t, short* __restrict__ x3i)
{
  const int bid = blockIdx.x;
  const int c8 = bid & 7;
  const int t8 = bid >> 3;
  const int rc = t8 % 48;
  const int pck = (t8 / 48) * 8 + c8;
  if (pck >= 98) return;

  const int lane = threadIdx.x;
  const int r0 = rc * 6;
  const int P = pck * 64 + lane;
  const int n = P / HWS;

  float acc[6];
  #pragma unroll
  for (int i = 0; i < 6; i++) {
    int r = r0 + i;
    acc[i] = (r < 16) ? b1[r] : (r < 32) ? b2[r - 16] : b3[r - 32];
  }

  const float* xc = x + (size_t)n * 256 * HWS + (P - n * HWS);
  const float* wt0 = wT + r0;
  #pragma unroll 16
  for (int c = 0; c < 256; c++) {
    float xv = xc[(size_t)c * HWS];
    const float* wt = wt0 + c * 288;
    #pragma unroll
    for (int i = 0; i < 6; i++)
      acc[i] = fmaf(wt[i], xv, acc[i]);
  }

  #pragma unroll
  for (int i = 0; i < 6; i++) {
    int r = r0 + i;
    if (r < 16)
      x1t[(size_t)P * 16 + r] = acc[i];
    else if (r < 32)
      x2t[(size_t)P * 16 + (r - 16)] = acc[i];
    else {
      float cl = fminf(fmaxf(acc[i], -15.9f), 15.9f);
      x3i[(size_t)P * 256 + (r - 32)] = (short)__float2int_rn(cl * X3SCALE);
    }
  }
}

// ---------------------------------------------------------------------------
// Kernel 2: closed-form BN1 stat parts (box-sum computed inline, 49 reads).
// parts: [c*5 + {S1,SS1,C,W2,W2S}] c<16, then [80..83] = pos sums.
// ---------------------------------------------------------------------------
__global__ __launch_bounds__(256) void k_bn1(
    const float* __restrict__ x1t, const float* __restrict__ x2t,
    const float* __restrict__ small, float* __restrict__ parts)
{
  __shared__ float cxs[56];
  __shared__ float red[4][4][20];
  __shared__ float pred[4][4];
  const int tid = threadIdx.x;
  if (tid < 56) {
    int cnt = 0;
    for (int xx = 0; xx < 56; xx++)
      for (int d = -3; d <= 3; d++)
        if (refl(xx + d) == tid) cnt++;
    cxs[tid] = (float)cnt;
  }
  __syncthreads();

  const int idx = blockIdx.x * 256 + tid;     // 98*256 = 6272*4
  const int p = idx >> 2, cq = (idx & 3) * 4;
  const int n = p / HWS, q = p % HWS;
  const int y = q / WID, xx = q - y * WID;

  int ry[7], rx[7];
  #pragma unroll
  for (int d = 0; d < 7; d++) { ry[d] = refl(y + d - 3); rx[d] = refl(xx + d - 3); }

  float4 x1v = *(const float4*)(x1t + (size_t)p * 16 + cq);
  float4 x2v = *(const float4*)(x2t + (size_t)p * 16 + cq);
  float4 b2 = {0.f, 0.f, 0.f, 0.f};
  #pragma unroll
  for (int a = 0; a < 7; a++) {
    const float* base = x2t + (size_t)(n * HWS + ry[a] * WID) * 16 + cq;
    #pragma unroll
    for (int b = 0; b < 7; b++) {
      float4 v = *(const float4*)(base + (size_t)rx[b] * 16);
      b2.x += v.x; b2.y += v.y; b2.z += v.z; b2.w += v.w;
    }
  }
  float cnt = cxs[y] * cxs[xx];

  float a[20];
  {
    float xv[4] = {x1v.x, x1v.y, x1v.z, x1v.w};
    float x2a[4] = {x2v.x, x2v.y, x2v.z, x2v.w};
    float bb[4] = {b2.x, b2.y, b2.z, b2.w};
    #pragma unroll
    for (int j = 0; j < 4; j++) {
      a[j*5+0] = xv[j];
      a[j*5+1] = xv[j] * xv[j];
      a[j*5+2] = xv[j] * bb[j];
      a[j*5+3] = cnt * x2a[j];
      a[j*5+4] = cnt * x2a[j] * x2a[j];
    }
  }
  #pragma unroll
  for (int i = 0; i < 20; i++) {
    #pragma unroll
    for (int off = 4; off <= 32; off <<= 1)
      a[i] += __shfl_xor(a[i], off);
  }
  const int lane = tid & 63, wv = tid >> 6;
  if (lane < 4) {
    #pragma unroll
    for (int i = 0; i < 20; i++) red[wv][lane][i] = a[i];
  }

  float ps[4] = {0.f, 0.f, 0.f, 0.f};
  const float wp00 = small[S_WP+0], wp01 = small[S_WP+1];
  const float wp10 = small[S_WP+2], wp11 = small[S_WP+3];
  for (int it = idx; it < 153664; it += 25088) {
    int k = it / 3136, qq = it - (it / 3136) * 3136;
    int yy = qq / WID, xq = qq - yy * WID;
    int ny = refl(yy + k / 7 - 3), nx = refl(xq + k % 7 - 3);
    float dlw = (float)(xq - nx) * (2.f / 55.f);
    float dlh = (float)(yy - ny) * (2.f / 55.f);
    float v16 = wp00 * dlw + wp01 * dlh;
    float v17 = wp10 * dlw + wp11 * dlh;
    ps[0] += v16; ps[1] += v16 * v16;
    ps[2] += v17; ps[3] += v17 * v17;
  }
  #pragma unroll
  for (int i = 0; i < 4; i++) {
    #pragma unroll
    for (int off = 1; off <= 32; off <<= 1)
      ps[i] += __shfl_xor(ps[i], off);
  }
  if (lane == 0) {
    #pragma unroll
    for (int i = 0; i < 4; i++) pred[wv][i] = ps[i];
  }
  __syncthreads();

  if (tid < 80) {
    int cq2 = tid / 20, v = tid % 20;
    float t = red[0][cq2][v] + red[1][cq2][v] + red[2][cq2][v] + red[3][cq2][v];
    int c = cq2 * 4 + v / 5, qty = v % 5;
    atomicAdd(&parts[c * 5 + qty], t);
  } else if (tid < 84) {
    int i = tid - 80;
    float t = pred[0][i] + pred[1][i] + pred[2][i] + pred[3][i];
    atomicAdd(&parts[80 + i], 2.0f * t);   // x2 for the two n
  }
}

// ---------------------------------------------------------------------------
// Kernel 3: BN2 statistics. Derives bn1 affine from `parts` in the preamble
// (comb folded in); block 0 publishes gsum1 for k_final. 784 blocks.
// ---------------------------------------------------------------------------
__global__ __launch_bounds__(256) void k_stats2(
    const float* __restrict__ x1t, const float* __restrict__ x2t,
    const float* __restrict__ small, const float* __restrict__ parts,
    float* __restrict__ gsum1, float* __restrict__ gsum2)
{
  __shared__ float red[4][32];
  const int tid = threadIdx.x;
  const float inv = 1.f / NKQ;
  float S[18], SS[18], sc1r[18], sh1r[18];
  #pragma unroll
  for (int c = 0; c < 16; c++) {
    S[c]  = 49.f * parts[c*5+0] - parts[c*5+3];
    SS[c] = 49.f * parts[c*5+1] - 2.f * parts[c*5+2] + parts[c*5+4];
  }
  S[16] = parts[80]; SS[16] = parts[81];
  S[17] = parts[82]; SS[17] = parts[83];
  #pragma unroll
  for (int c = 0; c < 18; c++) {
    float m = S[c] * inv;
    float var = SS[c] * inv - m * m;
    float sc = small[S_G1 + c] * rsqrtf(var + 1e-5f);
    sc1r[c] = sc; sh1r[c] = small[S_BE1 + c] - m * sc;
  }
  if (blockIdx.x == 0 && tid < 18) {
    gsum1[tid] = S[tid]; gsum1[18 + tid] = SS[tid];
  }

  const int bid = blockIdx.x;              // 784 = 2n * 49k * 8
  const int n = bid / 392;
  const int r = bid % 392;
  const int k = r >> 3, eig = r & 7;
  const int ki = k / 7 - 3, kj = k % 7 - 3;
  const float wp00 = small[S_WP+0], wp01 = small[S_WP+1];
  const float wp10 = small[S_WP+2], wp11 = small[S_WP+3];
  const float* cw1f = small + S_CW1;
  float s[16], ss[16];
  #pragma unroll
  for (int i = 0; i < 16; i++) { s[i] = 0.f; ss[i] = 0.f; }

  for (int qq = tid; qq < 392; qq += 256) {
    int q = eig * 392 + qq;
    int y = q / WID, xx = q - y * WID;
    int ny = refl(y + ki), nx = refl(xx + kj);
    int nb = ny * WID + nx;
    float t1v[18];
    const float4* a4 = (const float4*)(x1t + (size_t)(n * HWS + q) * 16);
    const float4* b4 = (const float4*)(x2t + (size_t)(n * HWS + nb) * 16);
    #pragma unroll
    for (int r4 = 0; r4 < 4; r4++) {
      float4 av = a4[r4], bv = b4[r4];
      t1v[r4*4+0] = av.x - bv.x; t1v[r4*4+1] = av.y - bv.y;
      t1v[r4*4+2] = av.z - bv.z; t1v[r4*4+3] = av.w - bv.w;
    }
    float dlw = (float)(xx - nx) * (2.f / 55.f);
    float dlh = (float)(y - ny) * (2.f / 55.f);
    t1v[16] = wp00 * dlw + wp01 * dlh;
    t1v[17] = wp10 * dlw + wp11 * dlh;
    #pragma unroll
    for (int c = 0; c < 18; c++) t1v[c] = fmaxf(fmaf(t1v[c], sc1r[c], sh1r[c]), 0.f);
    #pragma unroll
    for (int r2 = 0; r2 < 16; r2++) {
      float acc = 0.f;
      #pragma unroll
      for (int c = 0; c < 18; c++) acc = fmaf(cw1f[r2 * 18 + c], t1v[c], acc);
      s[r2] += acc; ss[r2] += acc * acc;
    }
  }

  #pragma unroll
  for (int i = 0; i < 16; i++) {
    #pragma unroll
    for (int off = 32; off > 0; off >>= 1) {
      s[i]  += __shfl_down(s[i], off);
      ss[i] += __shfl_down(ss[i], off);
    }
  }
  const int wvv = tid >> 6, lane = tid & 63;
  if (lane == 0) {
    #pragma unroll
    for (int i = 0; i < 16; i++) { red[wvv][i] = s[i]; red[wvv][16 + i] = ss[i]; }
  }
  __syncthreads();
  if (tid < 32) {
    float t = red[0][tid] + red[1][tid] + red[2][tid] + red[3][tid];
    atomicAdd(&gsum2[tid], t);
  }
}

// ---------------------------------------------------------------------------
// Kernel 4: 4 waves/block, one wave per pixel. Deferred-normalization
// softmax (half e in LDS); lane owns channels 4l..4l+3 (one group g = l>>1)
// -> one coalesced int2 x3 load per k.
// ---------------------------------------------------------------------------
__global__ __launch_bounds__(256) void k_final(
    const float* __restrict__ x1t, const float* __restrict__ x2t,
    const short* __restrict__ x3i, const float* __restrict__ small,
    const float* __restrict__ gsum1, const float* __restrict__ gsum2,
    float* __restrict__ outf)
{
  __shared__ __half wwh[4][49][34];
  __shared__ int nbs[4][49];
  __shared__ float sc1s[18], sh1s[18], sc2s[16], sh2s[16];

  const int tid = threadIdx.x;
  const int lane = tid & 63;
  const int wv = tid >> 6;
  const float inv = 1.f / NKQ;

  if (tid < 18) {
    float m = gsum1[tid] * inv;
    float var = gsum1[18 + tid] * inv - m * m;
    float sc = small[S_G1 + tid] * rsqrtf(var + 1e-5f);
    sc1s[tid] = sc; sh1s[tid] = small[S_BE1 + tid] - m * sc;
  } else if (tid >= 32 && tid < 48) {
    int c = tid - 32;
    float m = gsum2[c] * inv;
    float var = gsum2[16 + c] * inv - m * m;
    float sc = small[S_G2 + c] * rsqrtf(var + 1e-5f);
    sc2s[c] = sc; sh2s[c] = small[S_BE2 + c] - m * sc;
  }
  __syncthreads();

  const int P = blockIdx.x * 4 + wv;   // grid = 1568
  const int n = P / HWS, q = P % HWS;
  const int y = q / WID, xx = q - y * WID;

  const bool valid = lane < 49;
  const int kk = valid ? lane : 48;
  const int ki = kk / 7 - 3, kj = kk % 7 - 3;
  const int ny = refl(y + ki), nx = refl(xx + kj);
  const int nb = ny * WID + nx;
  if (valid) nbs[wv][lane] = nb;

  float t1v[18];
  {
    const float4* a4 = (const float4*)(x1t + (size_t)(n * HWS + q) * 16);
    const float4* b4 = (const float4*)(x2t + (size_t)(n * HWS + nb) * 16);
    #pragma unroll
    for (int r4 = 0; r4 < 4; r4++) {
      float4 av = a4[r4], bv = b4[r4];
      t1v[r4*4+0] = av.x - bv.x; t1v[r4*4+1] = av.y - bv.y;
      t1v[r4*4+2] = av.z - bv.z; t1v[r4*4+3] = av.w - bv.w;
    }
    float dlw = (float)(xx - nx) * (2.f / 55.f);
    float dlh = (float)(y - ny) * (2.f / 55.f);
    t1v[16] = small[S_WP+0] * dlw + small[S_WP+1] * dlh;
    t1v[17] = small[S_WP+2] * dlw + small[S_WP+3] * dlh;
  }
  #pragma unroll
  for (int c = 0; c < 18; c++)
    t1v[c] = fmaxf(fmaf(t1v[c], sc1s[c], sh1s[c]), 0.f);

  float t2v[16];
  #pragma unroll
  for (int r = 0; r < 16; r++) {
    float acc = 0.f;
    #pragma unroll
    for (int c = 0; c < 18; c++) acc = fmaf(small[S_CW1 + r * 18 + c], t1v[c], acc);
    t2v[r] = fmaxf(fmaf(acc, sc2s[r], sh2s[r]), 0.f);
  }

  #pragma unroll
  for (int g2 = 0; g2 < 32; g2++) {
    float acc = small[S_CB2 + g2];
    #pragma unroll
    for (int r = 0; r < 16; r++) acc = fmaf(small[S_CW2 + g2 * 16 + r], t2v[r], acc);
    if (valid) wwh[wv][lane][g2] = __float2half(__expf(acc));
  }
  __syncthreads();

  const short* x3p = x3i + (size_t)n * HWS * 256;
  const int* nbp = nbs[wv];
  const __half (*wh)[34] = wwh[wv];
  const int g = lane >> 1;
  const int o0 = lane * 4;
  float acc0 = 0.f, acc1 = 0.f, acc2 = 0.f, acc3 = 0.f, wsum = 0.f;
  #pragma unroll 7
  for (int k = 0; k < 49; k++) {
    const int2 d = *(const int2*)(x3p + (size_t)nbp[k] * 256 + o0);
    float w = __half2float(wh[k][g]);
    wsum += w;
    acc0 = fmaf(w, (float)(short)(d.x & 0xffff), acc0);
    acc1 = fmaf(w, (float)(short)(d.x >> 16),    acc1);
    acc2 = fmaf(w, (float)(short)(d.y & 0xffff), acc2);
    acc3 = fmaf(w, (float)(short)(d.y >> 16),    acc3);
  }
  const float sc = X3INV / wsum;
  const size_t ob = (size_t)(n * 256 + o0) * HWS + q;
  outf[ob]           = acc0 * sc;
  outf[ob + HWS]     = acc1 * sc;
  outf[ob + 2 * HWS] = acc2 * sc;
  outf[ob + 3 * HWS] = acc3 * sc;
}

// ---------------------------------------------------------------------------
extern "C" void kernel_launch(void* const* d_in, const int* in_sizes, int n_in,
                              void* d_out, int out_size, void* d_ws, size_t ws_size,
                              hipStream_t stream) {
  (void)in_sizes; (void)n_in; (void)out_size; (void)ws_size;
  char* ws = (char*)d_ws;
  float* gbase = (float*)(ws + 0);       // 176 f32 zeroed by k_prep
  float* gsum1 = (float*)(ws + 0);       // 36 f32
  float* gsum2 = (float*)(ws + 160);     // 32 f32
  float* parts = (float*)(ws + 320);     // 84 f32 (ends 656)
  float* small = (float*)(ws + 704);     // S_TOT f32 (ends 4320)
  float* x1t   = (float*)(ws + 4608);    // 2*3136*16 f32
  float* x2t   = (float*)(ws + 406016);  // 2*3136*16 f32
  short* x3i   = (short*)(ws + 807424);  // 2*3136*256 i16 (ends 4018688)
  float* outf  = (float*)d_out;
  float* wT    = (float*)d_out;          // scratch (overwritten by k_final)

  const float* x   = (const float*)d_in[0];
  const float* w1  = (const float*)d_in[1];
  const float* b1  = (const float*)d_in[2];
  const float* w2  = (const float*)d_in[3];
  const float* b2  = (const float*)d_in[4];
  const float* w3  = (const float*)d_in[5];
  const float* b3  = (const float*)d_in[6];
  const float* wp  = (const float*)d_in[7];
  const float* g1  = (const float*)d_in[9];
  const float* be1 = (const float*)d_in[10];
  const float* cw1 = (const float*)d_in[11];
  const float* g2  = (const float*)d_in[12];
  const float* be2 = (const float*)d_in[13];
  const float* cw2 = (const float*)d_in[14];
  const float* cb2 = (const float*)d_in[15];

  k_prep<<<292, 256, 0, stream>>>(w1, w2, w3, cw1, cw2, cb2, wp,
                                  g1, be1, g2, be2, small, wT, gbase);
  k_proj<<<4992, 64, 0, stream>>>(x, wT, b1, b2, b3, x1t, x2t, x3i);
  k_bn1<<<98, 256, 0, stream>>>(x1t, x2t, small, parts);
  k_stats2<<<784, 256, 0, stream>>>(x1t, x2t, small, parts, gsum1, gsum2);
  k_final<<<1568, 256, 0, stream>>>(x1t, x2t, x3i, small, gsum1, gsum2, outf);
}